// Round 1
// baseline (1132.337 us; speedup 1.0000x reference)
//
#include <hip/hip_runtime.h>
#include <math.h>

#define N_TOTAL   262144      // 256 graphs * 1024 nodes
#define E_TOTAL   8388608     // N_TOTAL * 32
#define D_FEAT    128
#define NUM_G     256
#define NPG       1024
#define KSEL      820         // ceil(0.8 * 1024)
#define BK        (NUM_G * KSEL)   // 209920

// ---------------------------------------------------------------------------
// K1: xw[i] = dot(x[i,:], W[:,0]) in double. One wave (64 lanes) per node,
// each lane loads a float2 (coalesced 8B/lane).
// ---------------------------------------------------------------------------
__global__ void xw_kernel(const float* __restrict__ x, const float* __restrict__ W,
                          double* __restrict__ xw) {
    int gtid = blockIdx.x * blockDim.x + threadIdx.x;
    int node = gtid >> 6;
    int lane = threadIdx.x & 63;
    if (node >= N_TOTAL) return;
    float2 xv = ((const float2*)x)[(size_t)node * 64 + lane];
    float2 wv = ((const float2*)W)[lane];
    double s = (double)xv.x * (double)wv.x + (double)xv.y * (double)wv.y;
    #pragma unroll
    for (int off = 32; off > 0; off >>= 1) s += __shfl_down(s, off, 64);
    if (lane == 0) xw[node] = s;
}

// ---------------------------------------------------------------------------
// K2: deg count over dst (self-loop +1 applied later).
// ---------------------------------------------------------------------------
__global__ void deg_kernel(const int* __restrict__ dst, int* __restrict__ deg) {
    int e = blockIdx.x * blockDim.x + threadIdx.x;
    if (e < E_TOTAL) atomicAdd(&deg[dst[e]], 1);
}

// ---------------------------------------------------------------------------
// K3: agg[d] += dinv[s]*dinv[d]*xw[s] per edge, double atomics.
// ---------------------------------------------------------------------------
__global__ void agg_kernel(const int* __restrict__ ei, const int* __restrict__ deg,
                           const double* __restrict__ xw, double* __restrict__ agg) {
    int e = blockIdx.x * blockDim.x + threadIdx.x;
    if (e >= E_TOTAL) return;
    int s = ei[e];
    int d = ei[e + E_TOTAL];
    double dinv_s = 1.0 / sqrt((double)(deg[s] + 1));
    double dinv_d = 1.0 / sqrt((double)(deg[d] + 1));
    atomicAdd(&agg[d], dinv_s * dinv_d * xw[s]);
}

// ---------------------------------------------------------------------------
// K4: score[i] = agg[i] + xw[i]/deg[i] + b
// ---------------------------------------------------------------------------
__global__ void score_kernel(const double* __restrict__ agg, const double* __restrict__ xw,
                             const int* __restrict__ deg, const float* __restrict__ b,
                             double* __restrict__ score) {
    int i = blockIdx.x * blockDim.x + threadIdx.x;
    if (i >= N_TOTAL) return;
    double dg = (double)(deg[i] + 1);
    score[i] = agg[i] + xw[i] * (1.0 / dg) + (double)b[0];
}

// ---------------------------------------------------------------------------
// K5: per-graph exact top-k by rank counting. One block (256 thr) per graph.
// rank_i = #{ j : s_j > s_i  or  (s_j == s_i and j < i) }  -- reproduces
// jax.lax.top_k's descending order with lower-index-first tie break.
// Emits perm (int + float out), node_map, new_batch.
// ---------------------------------------------------------------------------
__global__ void topk_kernel(const double* __restrict__ score,
                            int* __restrict__ permInt, int* __restrict__ node_map,
                            float* __restrict__ out_batch, float* __restrict__ out_perm) {
    __shared__ double s[NPG];
    int g = blockIdx.x;
    const double* sg = score + (size_t)g * NPG;
    for (int i = threadIdx.x; i < NPG; i += 256) s[i] = sg[i];
    __syncthreads();
    #pragma unroll
    for (int q = 0; q < 4; q++) {
        int i = threadIdx.x + 256 * q;
        double si = s[i];
        int rank = 0;
        for (int j = 0; j < NPG; j++) {
            double sj = s[j];
            rank += (sj > si) || (sj == si && j < i);
        }
        if (rank < KSEL) {
            int pos  = g * KSEL + rank;
            int node = g * NPG + i;
            permInt[pos]  = node;
            node_map[node] = pos;
            out_batch[pos] = (float)g;
            out_perm[pos]  = (float)node;
        }
    }
}

// ---------------------------------------------------------------------------
// K6: gather retained rows; x_ae = x[perm], x_out = x_ae * tanh(score[perm]).
// 32 lanes per row (float4/lane), 2 rows per wave.
// ---------------------------------------------------------------------------
__global__ void gather_kernel(const float* __restrict__ x, const double* __restrict__ score,
                              const int* __restrict__ permInt,
                              float* __restrict__ out_xout, float* __restrict__ out_xae) {
    int gtid = blockIdx.x * blockDim.x + threadIdx.x;
    int row  = gtid >> 5;
    int lane = gtid & 31;
    if (row >= BK) return;
    int node = permInt[row];
    float t = (float)tanh(score[node]);
    float4 v = ((const float4*)x)[(size_t)node * 32 + lane];
    float4 o = make_float4(v.x * t, v.y * t, v.z * t, v.w * t);
    ((float4*)out_xae)[(size_t)row * 32 + lane]  = v;
    ((float4*)out_xout)[(size_t)row * 32 + lane] = o;
}

// ---------------------------------------------------------------------------
// K7: edge outputs: mask + reindexed edge_index (kept edges), -1 elsewhere.
// ---------------------------------------------------------------------------
__global__ void edge_kernel(const int* __restrict__ ei, const int* __restrict__ node_map,
                            float* __restrict__ out_ei0, float* __restrict__ out_ei1,
                            float* __restrict__ out_mask) {
    int e = blockIdx.x * blockDim.x + threadIdx.x;
    if (e >= E_TOTAL) return;
    int s = ei[e];
    int d = ei[e + E_TOTAL];
    int ms = node_map[s];
    int md = node_map[d];
    bool m = (ms >= 0) && (md >= 0);
    out_ei0[e]  = m ? (float)ms : -1.0f;
    out_ei1[e]  = m ? (float)md : -1.0f;
    out_mask[e] = m ? 1.0f : 0.0f;
}

extern "C" void kernel_launch(void* const* d_in, const int* in_sizes, int n_in,
                              void* d_out, int out_size, void* d_ws, size_t ws_size,
                              hipStream_t stream) {
    const float* x  = (const float*)d_in[0];
    const int*   ei = (const int*)d_in[1];     // [2, E]: src then dst
    // d_in[2] = batch (unused; graphs are block-contiguous, recomputed)
    const float* W  = (const float*)d_in[3];
    const float* b  = (const float*)d_in[4];

    // workspace layout
    double* xw       = (double*)d_ws;            // N doubles
    double* agg      = xw + N_TOTAL;             // N doubles
    double* score    = agg + N_TOTAL;            // N doubles
    int*    deg      = (int*)(score + N_TOTAL);  // N ints
    int*    node_map = deg + N_TOTAL;            // N ints
    int*    permInt  = node_map + N_TOTAL;       // BK ints

    // output layout (all float32, concatenated in reference return order)
    float* out       = (float*)d_out;
    float* out_xout  = out;                          // BK*128
    float* out_ei0   = out + (size_t)BK * D_FEAT;    // E
    float* out_ei1   = out_ei0 + E_TOTAL;            // E
    float* out_mask  = out_ei1 + E_TOTAL;            // E
    float* out_batch = out_mask + E_TOTAL;           // BK
    float* out_perm  = out_batch + BK;               // BK
    float* out_xae   = out_perm + BK;                // BK*128

    hipMemsetAsync(agg, 0, (size_t)N_TOTAL * sizeof(double), stream);
    hipMemsetAsync(deg, 0, (size_t)N_TOTAL * sizeof(int), stream);
    hipMemsetAsync(node_map, 0xFF, (size_t)N_TOTAL * sizeof(int), stream);  // -1

    xw_kernel<<<(N_TOTAL * 64) / 256, 256, 0, stream>>>(x, W, xw);
    deg_kernel<<<E_TOTAL / 256, 256, 0, stream>>>(ei + E_TOTAL, deg);
    agg_kernel<<<E_TOTAL / 256, 256, 0, stream>>>(ei, deg, xw, agg);
    score_kernel<<<N_TOTAL / 256, 256, 0, stream>>>(agg, xw, deg, b, score);
    topk_kernel<<<NUM_G, 256, 0, stream>>>(score, permInt, node_map, out_batch, out_perm);
    gather_kernel<<<(BK * 32 + 255) / 256, 256, 0, stream>>>(x, score, permInt, out_xout, out_xae);
    edge_kernel<<<E_TOTAL / 256, 256, 0, stream>>>(ei, node_map, out_ei0, out_ei1, out_mask);
}

// Round 2
// 532.353 us; speedup vs baseline: 2.1270x; 2.1270x over previous
//
#include <hip/hip_runtime.h>
#include <math.h>

#define N_TOTAL   262144      // 256 graphs * 1024 nodes
#define E_TOTAL   8388608     // N_TOTAL * 32
#define EPG       32768       // edges per graph
#define D_FEAT    128
#define NUM_G     256
#define NPG       1024
#define KSEL      820         // ceil(0.8 * 1024)
#define BK        (NUM_G * KSEL)   // 209920

#define FP_SCALE     4503599627370496.0   // 2^52: fixed-point scale for deterministic agg
#define FP_INV_SCALE (1.0 / FP_SCALE)

// ---------------------------------------------------------------------------
// K1: xw[i] = dot(x[i,:], W[:,0]) in double. One wave (64 lanes) per node,
// each lane loads a float2 (coalesced 8B/lane).
// ---------------------------------------------------------------------------
__global__ void xw_kernel(const float* __restrict__ x, const float* __restrict__ W,
                          double* __restrict__ xw) {
    int gtid = blockIdx.x * blockDim.x + threadIdx.x;
    int node = gtid >> 6;
    int lane = threadIdx.x & 63;
    if (node >= N_TOTAL) return;
    float2 xv = ((const float2*)x)[(size_t)node * 64 + lane];
    float2 wv = ((const float2*)W)[lane];
    double s = (double)xv.x * (double)wv.x + (double)xv.y * (double)wv.y;
    #pragma unroll
    for (int off = 32; off > 0; off >>= 1) s += __shfl_down(s, off, 64);
    if (lane == 0) xw[node] = s;
}

// ---------------------------------------------------------------------------
// K2 (fused, one block of 1024 threads per graph):
//   deg (LDS int atomics) -> dinv -> agg (LDS int64 fixed-point atomics,
//   deterministic) -> score -> rank-count top-k -> local node map ->
//   edge outputs. Everything stays in LDS; zero global atomics.
// ---------------------------------------------------------------------------
__global__ __launch_bounds__(1024, 1)
void graph_kernel(const int* __restrict__ ei, const double* __restrict__ xw,
                  const float* __restrict__ bptr,
                  int* __restrict__ permInt, float* __restrict__ scaleF,
                  float* __restrict__ out_batch, float* __restrict__ out_perm,
                  float* __restrict__ out_ei0, float* __restrict__ out_ei1,
                  float* __restrict__ out_mask) {
    __shared__ double    xwS[NPG];     // 8 KB
    __shared__ int       degS[NPG];    // 4 KB
    __shared__ double    dinvS[NPG];   // 8 KB
    __shared__ long long aggS[NPG];    // 8 KB
    __shared__ float     scoreS[NPG];  // 4 KB
    __shared__ int       lmap[NPG];    // 4 KB   -> 36 KB total

    const int g    = blockIdx.x;
    const int tid  = threadIdx.x;
    const int base = g * NPG;
    const int4* src4 = (const int4*)(ei + (size_t)g * EPG);
    const int4* dst4 = (const int4*)(ei + E_TOTAL + (size_t)g * EPG);

    xwS[tid]  = xw[base + tid];
    degS[tid] = 0;
    aggS[tid] = 0;
    __syncthreads();

    // --- degree (in-edges) ---
    #pragma unroll
    for (int k = 0; k < 8; k++) {
        int4 d = dst4[tid + k * 1024];
        atomicAdd(&degS[d.x - base], 1);
        atomicAdd(&degS[d.y - base], 1);
        atomicAdd(&degS[d.z - base], 1);
        atomicAdd(&degS[d.w - base], 1);
    }
    __syncthreads();
    dinvS[tid] = 1.0 / sqrt((double)(degS[tid] + 1));
    __syncthreads();

    // --- aggregate: agg[d] += dinv[s]*dinv[d]*xw[s], int64 fixed point ---
    #pragma unroll
    for (int k = 0; k < 8; k++) {
        int4 s = src4[tid + k * 1024];
        int4 d = dst4[tid + k * 1024];
        int sx = s.x - base, sy = s.y - base, sz = s.z - base, sw = s.w - base;
        int dx = d.x - base, dy = d.y - base, dz = d.z - base, dw = d.w - base;
        double tx = dinvS[sx] * dinvS[dx] * xwS[sx];
        double ty = dinvS[sy] * dinvS[dy] * xwS[sy];
        double tz = dinvS[sz] * dinvS[dz] * xwS[sz];
        double tw = dinvS[sw] * dinvS[dw] * xwS[sw];
        atomicAdd((unsigned long long*)&aggS[dx], (unsigned long long)(long long)(tx * FP_SCALE));
        atomicAdd((unsigned long long*)&aggS[dy], (unsigned long long)(long long)(ty * FP_SCALE));
        atomicAdd((unsigned long long*)&aggS[dz], (unsigned long long)(long long)(tz * FP_SCALE));
        atomicAdd((unsigned long long*)&aggS[dw], (unsigned long long)(long long)(tw * FP_SCALE));
    }
    __syncthreads();

    // --- score ---
    {
        double dg = (double)(degS[tid] + 1);
        double sc = (double)aggS[tid] * FP_INV_SCALE + xwS[tid] * (1.0 / dg) + (double)bptr[0];
        scoreS[tid] = (float)sc;
    }
    __syncthreads();

    // --- exact top-k by rank counting (float compares, float4 broadcast) ---
    // rank_i = #{ j : s_j > s_i  or (s_j == s_i and j < i) }  == jax.lax.top_k order
    {
        float si = scoreS[tid];
        int rank = 0;
        const float4* s4 = (const float4*)scoreS;
        for (int j = 0; j < NPG / 4; j++) {
            float4 c = s4[j];
            int j0 = j * 4;
            rank += (c.x > si) || (c.x == si && (j0 + 0) < tid);
            rank += (c.y > si) || (c.y == si && (j0 + 1) < tid);
            rank += (c.z > si) || (c.z == si && (j0 + 2) < tid);
            rank += (c.w > si) || (c.w == si && (j0 + 3) < tid);
        }
        int pos = -1;
        if (rank < KSEL) {
            pos = g * KSEL + rank;
            int node = base + tid;
            permInt[pos]   = node;
            scaleF[pos]    = tanhf(si);
            out_batch[pos] = (float)g;
            out_perm[pos]  = (float)node;
        }
        lmap[tid] = pos;  // -1 if dropped; else global retained position
    }
    __syncthreads();

    // --- edge outputs: mask + reindexed endpoints (LDS-resident map) ---
    #pragma unroll
    for (int k = 0; k < 8; k++) {
        int idx = tid + k * 1024;               // int4 group within graph
        int4 s = src4[idx];
        int4 d = dst4[idx];
        float4 e0, e1, m;
        int ms, md; bool kp;
        ms = lmap[s.x - base]; md = lmap[d.x - base]; kp = (ms >= 0) && (md >= 0);
        e0.x = kp ? (float)ms : -1.0f; e1.x = kp ? (float)md : -1.0f; m.x = kp ? 1.0f : 0.0f;
        ms = lmap[s.y - base]; md = lmap[d.y - base]; kp = (ms >= 0) && (md >= 0);
        e0.y = kp ? (float)ms : -1.0f; e1.y = kp ? (float)md : -1.0f; m.y = kp ? 1.0f : 0.0f;
        ms = lmap[s.z - base]; md = lmap[d.z - base]; kp = (ms >= 0) && (md >= 0);
        e0.z = kp ? (float)ms : -1.0f; e1.z = kp ? (float)md : -1.0f; m.z = kp ? 1.0f : 0.0f;
        ms = lmap[s.w - base]; md = lmap[d.w - base]; kp = (ms >= 0) && (md >= 0);
        e0.w = kp ? (float)ms : -1.0f; e1.w = kp ? (float)md : -1.0f; m.w = kp ? 1.0f : 0.0f;
        size_t o = (size_t)g * (EPG / 4) + idx;
        ((float4*)out_ei0)[o]  = e0;
        ((float4*)out_ei1)[o]  = e1;
        ((float4*)out_mask)[o] = m;
    }
}

// ---------------------------------------------------------------------------
// K3: gather retained rows; x_ae = x[perm], x_out = x_ae * tanh(score[perm]).
// 32 lanes per row (float4/lane), tanh precomputed per row.
// ---------------------------------------------------------------------------
__global__ void gather_kernel(const float* __restrict__ x, const int* __restrict__ permInt,
                              const float* __restrict__ scaleF,
                              float* __restrict__ out_xout, float* __restrict__ out_xae) {
    int gtid = blockIdx.x * blockDim.x + threadIdx.x;
    int row  = gtid >> 5;
    int lane = gtid & 31;
    if (row >= BK) return;
    int node = permInt[row];
    float t = scaleF[row];
    float4 v = ((const float4*)x)[(size_t)node * 32 + lane];
    float4 o = make_float4(v.x * t, v.y * t, v.z * t, v.w * t);
    ((float4*)out_xae)[(size_t)row * 32 + lane]  = v;
    ((float4*)out_xout)[(size_t)row * 32 + lane] = o;
}

extern "C" void kernel_launch(void* const* d_in, const int* in_sizes, int n_in,
                              void* d_out, int out_size, void* d_ws, size_t ws_size,
                              hipStream_t stream) {
    const float* x  = (const float*)d_in[0];
    const int*   ei = (const int*)d_in[1];     // [2, E]: src then dst
    // d_in[2] = batch (unused; graphs are block-contiguous, recomputed)
    const float* W  = (const float*)d_in[3];
    const float* b  = (const float*)d_in[4];

    // workspace layout
    double* xw      = (double*)d_ws;           // N doubles
    int*    permInt = (int*)(xw + N_TOTAL);    // BK ints
    float*  scaleF  = (float*)(permInt + BK);  // BK floats

    // output layout (all float32, concatenated in reference return order)
    float* out       = (float*)d_out;
    float* out_xout  = out;                          // BK*128
    float* out_ei0   = out + (size_t)BK * D_FEAT;    // E
    float* out_ei1   = out_ei0 + E_TOTAL;            // E
    float* out_mask  = out_ei1 + E_TOTAL;            // E
    float* out_batch = out_mask + E_TOTAL;           // BK
    float* out_perm  = out_batch + BK;               // BK
    float* out_xae   = out_perm + BK;                // BK*128

    xw_kernel<<<(N_TOTAL * 64) / 256, 256, 0, stream>>>(x, W, xw);
    graph_kernel<<<NUM_G, 1024, 0, stream>>>(ei, xw, b, permInt, scaleF,
                                             out_batch, out_perm,
                                             out_ei0, out_ei1, out_mask);
    gather_kernel<<<(BK * 32 + 255) / 256, 256, 0, stream>>>(x, permInt, scaleF,
                                                             out_xout, out_xae);
}